// Round 4
// baseline (319.934 us; speedup 1.0000x reference)
//
#include <hip/hip_runtime.h>
#include <stdint.h>

// GraphConv x5 on MI355X — round 23.
// vs rounds 21/22 (FAILED): tr_read address model disambiguated by the two
// failures. ds_read_b64_tr_b16 takes a BYTE address where bits[6:3] select
// the column (0-15) and the 128B-aligned base selects the subtile; lane
// reads bytes (addr&~127) + ((addr>>3)&15)*2 + 32*j. (Round 22 falsified
// the packed addr[4:1]-column model; round 21 used byte base but column
// scale *2 -> column collapsed 4x.) Fix: trb = stgOff + (c>>4)*1024 +
// (c&15)*8, imm = byte offsets {0,512,128,640,...}. Everything else is
// round 21's MFMA-consume structure (per 32-edge sub-chunk: C[4n][64c] +=
// A[4x32 masked w] x B[32e x 64c] via 4 mfma_16x16x32_bf16; subtiled
// global_load_lds staging; A from bpermute of resident pairs reg).

#define NN 100000
#define NE 1600000
#define HID 64
#define NBKT 391            // ceil(NN/256), bucket = dst >> 8
#define CAP 8192            // padded bucket capacity (mean 4092, +64 sigma)
#define TILE 4096
#define EPT 16              // TILE / 256
#define NTILE ((NE + TILE - 1) / TILE)   // 391

typedef __attribute__((ext_vector_type(8))) short bf16x8;
typedef __attribute__((ext_vector_type(4))) float f32x4;
typedef __attribute__((ext_vector_type(2))) unsigned int u32x2;
typedef __attribute__((ext_vector_type(4))) unsigned int u32x4;

__device__ __forceinline__ uint32_t rne_bf16(float v) {
    uint32_t u = __float_as_uint(v);
    return (u + 0x7fffu + ((u >> 16) & 1u)) >> 16;
}

// ---------------- CSR build ----------------

// tile-local LDS counting sort + coalesced segment write-out
__global__ __launch_bounds__(256) void k_bpart(const int* __restrict__ src,
                                               const int* __restrict__ dst,
                                               const float* __restrict__ w,
                                               int* __restrict__ bcur,
                                               int2* __restrict__ bpairs) {
    __shared__ int  hcnt[NBKT];      // count, then cursor
    __shared__ int  hoff[NBKT];      // local exclusive offset
    __shared__ int  hadj[NBKT];      // global base - local offset
    __shared__ int  sc0[512];
    __shared__ int  sc1[512];
    __shared__ int2 sT[TILE];        // 32 KB staged tile (bucket-sorted)
    __shared__ int  sAdj[TILE];      // 16 KB per-slot global adjust
    int tile0 = blockIdx.x * TILE;
    int t = threadIdx.x;
    for (int i = t; i < NBKT; i += 256) hcnt[i] = 0;
    __syncthreads();

    int   pk[EPT];
    int   bk[EPT];
    float wv[EPT];
    #pragma unroll
    for (int k = 0; k < EPT; k++) {
        int e = tile0 + t + k * 256;
        if (e < NE) {
            int d = dst[e];
            int b = d >> 8;
            pk[k] = (src[e] << 8) | (d & 255);
            wv[k] = w[e];
            bk[k] = b;
            atomicAdd(&hcnt[b], 1);
        } else {
            bk[k] = -1;
        }
    }
    __syncthreads();

    // inclusive scan of hcnt over 512 (padded) with ping-pong buffers
    sc0[t]       = (t < NBKT) ? hcnt[t] : 0;
    sc0[t + 256] = (t + 256 < NBKT) ? hcnt[t + 256] : 0;
    __syncthreads();
    int* cur = sc0;
    int* oth = sc1;
    for (int off = 1; off < 512; off <<= 1) {
        int v0 = cur[t]       + ((t       >= off) ? cur[t - off]       : 0);
        int v1 = cur[t + 256] + ((t + 256 >= off) ? cur[t + 256 - off] : 0);
        oth[t] = v0;
        oth[t + 256] = v1;
        __syncthreads();
        int* tmp = cur; cur = oth; oth = tmp;
    }
    for (int i = t; i < NBKT; i += 256) {
        int c = hcnt[i];
        int excl = cur[i] - c;
        hoff[i] = excl;
        int gbase = c ? atomicAdd(&bcur[i], c) : 0;
        hadj[i] = gbase - excl;
        hcnt[i] = 0;                 // reuse as local cursor
    }
    __syncthreads();

    // scatter into LDS (bucket-sorted order)
    #pragma unroll
    for (int k = 0; k < EPT; k++) {
        if (bk[k] >= 0) {
            int b = bk[k];
            int pos = hoff[b] + atomicAdd(&hcnt[b], 1);
            sT[pos] = make_int2(pk[k], __float_as_int(wv[k]));
            sAdj[pos] = hadj[b];
        }
    }
    __syncthreads();

    // linear write-out: consecutive slots in a bucket run -> consecutive
    // global addresses (coalesced bursts)
    int n = NE - tile0; if (n > TILE) n = TILE;
    for (int j = t; j < n; j += 256)
        bpairs[sAdj[j] + j] = sT[j];
}

// one block per bucket: stage bucket in LDS, then LDS counting sort.
__global__ __launch_bounds__(256) void k_bcsr(const int* __restrict__ bcur,
                                              const int2* __restrict__ bpairs,
                                              int* __restrict__ offs,
                                              int* __restrict__ ends,
                                              uint32_t* __restrict__ pairs) {
    __shared__ int2 sE[CAP];        // 64 KB bucket stage
    __shared__ int cnt[256];
    __shared__ int scn[256];
    __shared__ int cur[256];
    int k = blockIdx.x, t = threadIdx.x;
    int base = k * CAP;
    int scnt = bcur[k] - base;
    cnt[t] = 0;
    __syncthreads();
    for (int j = t; j < scnt; j += 256) {
        int2 q = bpairs[base + j];
        sE[j] = q;
        atomicAdd(&cnt[q.x & 255], 1);
    }
    __syncthreads();
    int v = cnt[t], acc = v;
    scn[t] = v;
    __syncthreads();
    for (int off = 1; off < 256; off <<= 1) {
        int u = (t >= off) ? scn[t - off] : 0;
        __syncthreads();
        acc += u;
        scn[t] = acc;
        __syncthreads();
    }
    int excl = acc - v;
    cur[t] = excl;
    int d = (k << 8) + t;
    if (d < NN) {
        offs[d] = base + excl;
        ends[d] = base + excl + v;
    }
    __syncthreads();
    for (int j = t; j < scnt; j += 256) {
        int2 q = sE[j];
        int pos = base + atomicAdd(&cur[q.x & 255], 1);
        uint32_t wb = rne_bf16(__int_as_float(q.y)) & 0x7fffu;   // w >= 0
        pairs[pos] = (wb << 17) | (uint32_t)(q.x >> 8);
    }
}

// ---------------- weight hi/lo split (+ bucket cursor init) ----------------

__global__ __launch_bounds__(256) void k_wsplit(const float* __restrict__ Wrel_mid,
                                                const float* __restrict__ Wroot_mid,
                                                uint16_t* __restrict__ WgH,
                                                uint16_t* __restrict__ WgL,
                                                uint16_t* __restrict__ WrH,
                                                uint16_t* __restrict__ WrL,
                                                int* __restrict__ bcur) {
    int i = blockIdx.x * blockDim.x + threadIdx.x;
    if (i < NBKT) bcur[i] = i * CAP;
    if (i >= 3 * 4096) return;
    float a = Wrel_mid[i];
    uint32_t ah = rne_bf16(a);
    float al = a - __uint_as_float(ah << 16);
    WgH[i] = (uint16_t)ah;
    WgL[i] = (uint16_t)rne_bf16(al);
    float b = Wroot_mid[i];
    uint32_t bh = rne_bf16(b);
    float bl = b - __uint_as_float(bh << 16);
    WrH[i] = (uint16_t)bh;
    WrL[i] = (uint16_t)rne_bf16(bl);
}

// ---------------- shared epilogue: 16-node h (LDS) -> G,R via LDS tiles ----

__device__ __forceinline__ void mfma_epilogue(
        int lane, int w, const uint32_t* sH,
        const uint16_t* __restrict__ WgH, const uint16_t* __restrict__ WgL,
        const uint16_t* __restrict__ WrH, const uint16_t* __restrict__ WrL,
        const float* __restrict__ brel,
        uint16_t* sG, uint16_t* sR) {
    int row = lane & 15;
    int quad = lane >> 4;
    int kb = quad * 8;
    bf16x8 ah0 = *(const bf16x8*)&sH[row * 36 + quad * 4];
    bf16x8 ah1 = *(const bf16x8*)&sH[row * 36 + 16 + quad * 4];
    int oc = w * 16 + row;
    {
        bf16x8 bh0 = *(const bf16x8*)&WgH[oc * 64 + kb];
        bf16x8 bh1 = *(const bf16x8*)&WgH[oc * 64 + 32 + kb];
        bf16x8 bl0 = *(const bf16x8*)&WgL[oc * 64 + kb];
        bf16x8 bl1 = *(const bf16x8*)&WgL[oc * 64 + 32 + kb];
        f32x4 acc = {0.f, 0.f, 0.f, 0.f};
        acc = __builtin_amdgcn_mfma_f32_16x16x32_bf16(ah0, bh0, acc, 0, 0, 0);
        acc = __builtin_amdgcn_mfma_f32_16x16x32_bf16(ah1, bh1, acc, 0, 0, 0);
        acc = __builtin_amdgcn_mfma_f32_16x16x32_bf16(ah0, bl0, acc, 0, 0, 0);
        acc = __builtin_amdgcn_mfma_f32_16x16x32_bf16(ah1, bl1, acc, 0, 0, 0);
        #pragma unroll
        for (int r = 0; r < 4; r++)
            sG[(quad * 4 + r) * 68 + oc] = (uint16_t)rne_bf16(acc[r]);
    }
    {
        bf16x8 bh0 = *(const bf16x8*)&WrH[oc * 64 + kb];
        bf16x8 bh1 = *(const bf16x8*)&WrH[oc * 64 + 32 + kb];
        bf16x8 bl0 = *(const bf16x8*)&WrL[oc * 64 + kb];
        bf16x8 bl1 = *(const bf16x8*)&WrL[oc * 64 + 32 + kb];
        float bias = brel[oc];
        f32x4 acc = {bias, bias, bias, bias};
        acc = __builtin_amdgcn_mfma_f32_16x16x32_bf16(ah0, bh0, acc, 0, 0, 0);
        acc = __builtin_amdgcn_mfma_f32_16x16x32_bf16(ah1, bh1, acc, 0, 0, 0);
        acc = __builtin_amdgcn_mfma_f32_16x16x32_bf16(ah0, bl0, acc, 0, 0, 0);
        acc = __builtin_amdgcn_mfma_f32_16x16x32_bf16(ah1, bl1, acc, 0, 0, 0);
        #pragma unroll
        for (int r = 0; r < 4; r++)
            sR[(quad * 4 + r) * 68 + oc] = (uint16_t)rne_bf16(acc[r]);
    }
}

__device__ __forceinline__ void epilogue_writeout(
        int tid, int blk16, const uint16_t* sG, const uint16_t* sR,
        uint16_t* __restrict__ Gout, uint16_t* __restrict__ Rout) {
    const uint32_t* sGd = (const uint32_t*)sG;   // stride 34 dwords/node
    const uint32_t* sRd = (const uint32_t*)sR;
    uint32_t* Gd = (uint32_t*)Gout;
    uint32_t* Rd = (uint32_t*)Rout;
    #pragma unroll
    for (int it = 0; it < 2; it++) {
        int idx = it * 256 + tid;
        int nd = idx >> 5, col = idx & 31;
        Gd[(blk16 + nd) * 32 + col] = sGd[nd * 34 + col];
        Rd[(blk16 + nd) * 32 + col] = sRd[nd * 34 + col];
    }
}

// ---------------- layers ----------------

// layer 0 (fused): edge-parallel aggregation (all waves, shfl reduce), then
// h0 = relu(...) staged in LDS, MFMA epilogue -> G1,R1.
__global__ __launch_bounds__(256) void k_l0pre(
        const int* __restrict__ offs, const int* __restrict__ ends,
        const uint32_t* __restrict__ pairs, const float* __restrict__ x,
        const float* __restrict__ Wrel0, const float* __restrict__ brel0,
        const float* __restrict__ Wroot0,
        const uint16_t* __restrict__ WgH, const uint16_t* __restrict__ WgL,
        const uint16_t* __restrict__ WrH, const uint16_t* __restrict__ WrL,
        const float* __restrict__ brel,
        uint16_t* __restrict__ Gout, uint16_t* __restrict__ Rout) {
    __shared__ uint32_t sH[16 * 36];
    __shared__ uint16_t sG[16 * 68];
    __shared__ uint16_t sR[16 * 68];
    int c = threadIdx.x & 63;
    int w = threadIdx.x >> 6;
    int blk16 = blockIdx.x * 16;
    float agg[4];
    #pragma unroll
    for (int t = 0; t < 4; t++) {
        int node = blk16 + w * 4 + t;
        int b = offs[node], e = ends[node];
        float pp = 0.f;
        for (int j = b + c; j < e; j += 64) {
            uint32_t r = pairs[j];
            pp += __uint_as_float((r >> 17) << 16) * x[r & 0x1ffffu];
        }
        for (int o = 32; o > 0; o >>= 1) pp += __shfl_down(pp, o, 64);
        agg[t] = __shfl(pp, 0, 64);
    }
    float wr = Wrel0[c], br = brel0[c], wo = Wroot0[c];
    #pragma unroll
    for (int t = 0; t < 4; t++) {
        int node = blk16 + w * 4 + t;
        float v = agg[t] * wr + br + x[node] * wo;
        v = v > 0.f ? v : 0.f;
        uint32_t hb = rne_bf16(v);
        uint32_t pn = (uint32_t)__shfl_xor((int)hb, 1, 64);
        if (!(c & 1)) sH[(w * 4 + t) * 36 + (c >> 1)] = hb | (pn << 16);
    }
    __syncthreads();
    mfma_epilogue(c, w, sH, WgH, WgL, WrH, WrL, brel, sG, sR);
    __syncthreads();
    epilogue_writeout((int)threadIdx.x, blk16, sG, sR, Gout, Rout);
}

// transpose-read, byte-addressed: column = addr bits[6:3], subtile = the
// 128B-aligned base; lane reads bytes (addr&~127) + ((addr>>3)&15)*2 + 32*j
#define TRR(dst, off) \
    asm volatile("ds_read_b64_tr_b16 %0, %1 offset:" #off \
                 : "=v"(dst) : "v"(trb))

// Fused aggregation + pre-transform, MFMA consume (round 23).
template <bool LAST>
__global__ __launch_bounds__(256, 6) void k_aggfused(
        const int* __restrict__ offs, const int* __restrict__ ends,
        const uint32_t* __restrict__ pairs,
        const uint16_t* __restrict__ Gb, const uint16_t* __restrict__ Rb,
        const uint16_t* __restrict__ WgH, const uint16_t* __restrict__ WgL,
        const uint16_t* __restrict__ WrH, const uint16_t* __restrict__ WrL,
        const float* __restrict__ brel,
        uint16_t* __restrict__ Gout, uint16_t* __restrict__ Rout,
        const float* __restrict__ WrelL, const float* __restrict__ WrootL,
        float* __restrict__ sarr, float* __restrict__ rarr) {
    __shared__ uint32_t sH[16 * 36];
    // 4 waves x 4KB gather stage (subtiled layout); dead before the MFMA
    // epilogue, so sG/sR overlay it. 18688 B total -> 8 blocks/CU.
    __shared__ __align__(128) char smem[16384];
    int c = threadIdx.x & 63;
    int w = threadIdx.x >> 6;
    int blk16 = blockIdx.x * 16;
    int n0 = blk16 + w * 4;
    int ov = 0;
    if (c < 4) ov = offs[n0 + c];
    else if (c == 4) ov = ends[n0 + 3];
    int bnd[5];
    bnd[0] = __builtin_amdgcn_readlane(ov, 0);
    bnd[1] = __builtin_amdgcn_readlane(ov, 1);
    bnd[2] = __builtin_amdgcn_readlane(ov, 2);
    bnd[3] = __builtin_amdgcn_readlane(ov, 3);
    bnd[4] = __builtin_amdgcn_readlane(ov, 4);

    // ---- per-lane constants ----
    int arow  = c & 15;                       // A/C row (node 0..3 valid)
    int kq    = (c >> 4) * 8;                 // MFMA k-base for this quad
    // staging permutation: lane L fetches edge eprm of its 8-edge group,
    // cols c0 = ((L>>3)&3)*16 + (L&1)*8 so linear LDS dest == subtiled
    // layout: byte(e,col) = (e>>3)*1024 + ((e>>2)&1)*512 + (col>>4)*128
    //                      + (e&3)*32 + (col&15)*2
    int eprm  = ((c >> 5) << 2) | ((c >> 1) & 3);
    int lbyte = ((c >> 3) & 3) * 32 + (c & 1) * 16;
    char* stg = smem + w * 4096;
    uint32_t stgOff = (uint32_t)(uintptr_t)
        (__attribute__((address_space(3))) char*)stg;
    // byte-addressed tr base: 128B subtile base (i = c>>4 -> +1024*i) +
    // column (c&15) in bits[6:3]; imm adds nb*128 (+512 for e&4)
    uint32_t trb = stgOff + ((uint32_t)(c >> 4) << 10)
                          + ((uint32_t)(c & 15) << 3);

    // per-lane segment bounds for the A mask
    int blo = bnd[0], bhi = bnd[1];
    if (arow == 1) { blo = bnd[1]; bhi = bnd[2]; }
    if (arow == 2) { blo = bnd[2]; bhi = bnd[3]; }
    if (arow == 3) { blo = bnd[3]; bhi = bnd[4]; }
    if (arow >= 4) { blo = 0;      bhi = 0;      }
    uint32_t wid = (uint32_t)(bhi - blo);

    // zero-init stage once: masked-A x uninitialized-LDS could be NaN
    {
        f32x4 z = {0.f, 0.f, 0.f, 0.f};
        #pragma unroll
        for (int i = 0; i < 4; i++)
            *(f32x4*)(stg + i * 1024 + c * 16) = z;
        asm volatile("s_waitcnt lgkmcnt(0)" ::: "memory");
    }

    // C-init = root rows (Rb already holds Wroot*h + brel), redistributed
    // from the coalesced per-col layout into the C fragment layout.
    f32x4 acc16[4];
    {
        int ur[4];
        #pragma unroll
        for (int t = 0; t < 4; t++) ur[t] = (int)(uint32_t)Rb[(n0 + t) * 64 + c];
        #pragma unroll
        for (int nb = 0; nb < 4; nb++) {
            int idx = (nb * 16 + (c & 15)) * 4;
            f32x4 ci;
            #pragma unroll
            for (int t = 0; t < 4; t++) {
                uint32_t rv = (uint32_t)__builtin_amdgcn_ds_bpermute(idx, ur[t]);
                ci[t] = __uint_as_float(rv << 16);
            }
            acc16[nb] = ci;
        }
    }

    const char* gbase = (const char*)Gb;
    uint32_t p = 0;
    if (bnd[0] + c < bnd[4]) p = pairs[bnd[0] + c];

    for (int cb = bnd[0]; cb < bnd[4]; cb += 64) {
        uint32_t pnext = 0;
        if (cb + 64 + c < bnd[4]) pnext = pairs[cb + 64 + c];
        #pragma unroll
        for (int s = 0; s < 2; s++) {
            int sb = cb + s * 32;
            if (sb < bnd[4]) {
                int sn = bnd[4] - sb; if (sn > 32) sn = 32;
                int ni = (sn + 7) >> 3;
                int es4 = (s * 32 + eprm) * 4;
                #pragma unroll
                for (int i = 0; i < 4; i++) {
                    if (i < ni) {
                        uint32_t r = (uint32_t)__builtin_amdgcn_ds_bpermute(
                            es4 + i * 32, (int)p);
                        uint32_t voff = ((r & 0x1ffffu) << 7) + (uint32_t)lbyte;
                        __builtin_amdgcn_global_load_lds(
                            (const __attribute__((address_space(1))) void*)(gbase + voff),
                            (__attribute__((address_space(3))) void*)(stg + i * 1024),
                            16, 0, 0);
                    }
                }
                asm volatile("s_waitcnt vmcnt(0)" ::: "memory");
                // B fragments: 8 transpose reads; imm = nb*128 (+512 e&4)
                u32x2 tb0, tb1, tb2, tb3, tb4, tb5, tb6, tb7;
                TRR(tb0, 0);   TRR(tb1, 512);
                TRR(tb2, 128); TRR(tb3, 640);
                TRR(tb4, 256); TRR(tb5, 768);
                TRR(tb6, 384); TRR(tb7, 896);
                // A fragment: masked weights from the resident pairs reg
                int kidx = s * 128 + kq * 4;
                int db = sb + kq - blo;
                uint32_t m[8];
                #pragma unroll
                for (int q = 0; q < 8; q++) {
                    uint32_t rq = (uint32_t)__builtin_amdgcn_ds_bpermute(
                        kidx + q * 4, (int)p);
                    uint32_t bf = rq >> 17;   // bf16 bits (w >= 0)
                    m[q] = ((uint32_t)(db + q) < wid) ? bf : 0u;
                }
                u32x4 aa = { m[0] | (m[1] << 16), m[2] | (m[3] << 16),
                             m[4] | (m[5] << 16), m[6] | (m[7] << 16) };
                bf16x8 af = __builtin_bit_cast(bf16x8, aa);
                asm volatile("s_waitcnt lgkmcnt(0)" ::: "memory");
                __builtin_amdgcn_sched_barrier(0);
                {
                    u32x4 bb0 = { tb0.x, tb0.y, tb1.x, tb1.y };
                    acc16[0] = __builtin_amdgcn_mfma_f32_16x16x32_bf16(
                        af, __builtin_bit_cast(bf16x8, bb0), acc16[0], 0, 0, 0);
                    u32x4 bb1 = { tb2.x, tb2.y, tb3.x, tb3.y };
                    acc16[1] = __builtin_amdgcn_mfma_f32_16x16x32_bf16(
                        af, __builtin_bit_cast(bf16x8, bb1), acc16[1], 0, 0, 0);
                    u32x4 bb2 = { tb4.x, tb4.y, tb5.x, tb5.y };
                    acc16[2] = __builtin_amdgcn_mfma_f32_16x16x32_bf16(
                        af, __builtin_bit_cast(bf16x8, bb2), acc16[2], 0, 0, 0);
                    u32x4 bb3 = { tb6.x, tb6.y, tb7.x, tb7.y };
                    acc16[3] = __builtin_amdgcn_mfma_f32_16x16x32_bf16(
                        af, __builtin_bit_cast(bf16x8, bb3), acc16[3], 0, 0, 0);
                }
            }
        }
        p = pnext;
    }

    if (!LAST) {
        // lanes 0-15 hold C rows 0-3 (regs t) for cols nb*16+(c&15)
        #pragma unroll
        for (int t = 0; t < 4; t++) {
            #pragma unroll
            for (int nb = 0; nb < 4; nb++) {
                float v = acc16[nb][t];
                v = v > 0.f ? v : 0.f;
                uint32_t hb = rne_bf16(v);
                uint32_t pn2 = (uint32_t)__shfl_xor((int)hb, 1, 64);
                if (!(c & 1) && c < 16)
                    sH[(w * 4 + t) * 36 + nb * 8 + (c >> 1)] = hb | (pn2 << 16);
            }
        }
        __syncthreads();
        uint16_t* sG = (uint16_t*)smem;           // overlay on dead stage
        uint16_t* sR = (uint16_t*)(smem + 2176);
        mfma_epilogue(c, w, sH, WgH, WgL, WrH, WrL, brel, sG, sR);
        __syncthreads();
        epilogue_writeout((int)threadIdx.x, blk16, sG, sR, Gout, Rout);
    } else {
        float wl[4], wo[4];
        #pragma unroll
        for (int nb = 0; nb < 4; nb++) {
            wl[nb] = WrelL[nb * 16 + (c & 15)];
            wo[nb] = WrootL[nb * 16 + (c & 15)];
        }
        #pragma unroll
        for (int t = 0; t < 4; t++) {
            float pa = 0.f, pr = 0.f;
            #pragma unroll
            for (int nb = 0; nb < 4; nb++) {
                float v = acc16[nb][t];
                v = v > 0.f ? v : 0.f;
                pa += v * wl[nb];
                pr += v * wo[nb];
            }
            #pragma unroll
            for (int o = 8; o > 0; o >>= 1) {
                pa += __shfl_down(pa, o, 64);
                pr += __shfl_down(pr, o, 64);
            }
            if (c == 0) { sarr[n0 + t] = pa; rarr[n0 + t] = pr; }
        }
    }
}

__global__ void k_last(const int* __restrict__ offs, const int* __restrict__ ends,
                       const uint32_t* __restrict__ pairs,
                       const float* __restrict__ sarr, const float* __restrict__ rarr,
                       const float* __restrict__ brelL, float* __restrict__ out) {
    int i = blockIdx.x * blockDim.x + threadIdx.x;
    if (i >= NN) return;
    float a0 = rarr[i] + brelL[0], a1 = 0.f;
    int b = offs[i], e = ends[i];
    int j = b;
    for (; j + 2 <= e; j += 2) {
        uint32_t r0 = pairs[j], r1 = pairs[j + 1];
        a0 += __uint_as_float((r0 >> 17) << 16) * sarr[r0 & 0x1ffffu];
        a1 += __uint_as_float((r1 >> 17) << 16) * sarr[r1 & 0x1ffffu];
    }
    for (; j < e; j++) {
        uint32_t r = pairs[j];
        a0 += __uint_as_float((r >> 17) << 16) * sarr[r & 0x1ffffu];
    }
    out[i] = a0 + a1;
}

extern "C" void kernel_launch(void* const* d_in, const int* in_sizes, int n_in,
                              void* d_out, int out_size, void* d_ws, size_t ws_size,
                              hipStream_t stream) {
    const float* x        = (const float*)d_in[0];
    const int*   ei       = (const int*)d_in[1];
    const float* ew       = (const float*)d_in[2];
    const float* Wrel0    = (const float*)d_in[3];
    const float* brel0    = (const float*)d_in[4];
    const float* Wroot0   = (const float*)d_in[5];
    const float* Wrel_mid = (const float*)d_in[6];
    const float* brel_mid = (const float*)d_in[7];
    const float* Wroot_mid= (const float*)d_in[8];
    const float* WrelL    = (const float*)d_in[9];
    const float* brelL    = (const float*)d_in[10];
    const float* WrootL   = (const float*)d_in[11];
    float* out = (float*)d_out;

    const int* src  = ei;
    const int* dstp = ei + NE;

    char* w = (char*)d_ws;
    size_t o = 0;
    auto alloc = [&](size_t b) -> void* {
        void* r = (void*)(w + o);
        o += (b + 255) & ~(size_t)255;
        return r;
    };
    int*      offs  = (int*)alloc((size_t)NN * 4);
    int*      ends  = (int*)alloc((size_t)NN * 4);
    int*      bcur  = (int*)alloc((size_t)NBKT * 4);
    uint16_t* WgH   = (uint16_t*)alloc((size_t)3 * 4096 * 2);
    uint16_t* WgL   = (uint16_t*)alloc((size_t)3 * 4096 * 2);
    uint16_t* WrH   = (uint16_t*)alloc((size_t)3 * 4096 * 2);
    uint16_t* WrL   = (uint16_t*)alloc((size_t)3 * 4096 * 2);
    float*    sarr  = (float*)alloc((size_t)NN * 4);
    float*    rarr  = (float*)alloc((size_t)NN * 4);
    uint32_t* pairs = (uint32_t*)alloc((size_t)NBKT * CAP * 4);  // 12.8 MB padded
    uint16_t* GbA   = (uint16_t*)alloc((size_t)NN * HID * 2);    // 12.8 MB
    uint16_t* RbA   = (uint16_t*)alloc((size_t)NN * HID * 2);
    uint16_t* GbB   = (uint16_t*)alloc((size_t)NN * HID * 2);    // GbB/RbB contiguous
    uint16_t* RbB   = (uint16_t*)alloc((size_t)NN * HID * 2);
    (void)RbB;
    // bpairs (NBKT*CAP*8B = 25.6MB) aliases GbB+RbB (contiguous; dead before
    // mid layer 1 writes set B)
    int2*  bpairs = (int2*)GbB;

    // weight split + bucket cursor init (one launch)
    k_wsplit<<<(3 * 4096 + 255) / 256, 256, 0, stream>>>(
        Wrel_mid, Wroot_mid, WgH, WgL, WrH, WrL, bcur);

    // CSR build (padded buckets)
    k_bpart<<<NTILE, 256, 0, stream>>>(src, dstp, ew, bcur, bpairs);
    k_bcsr<<<NBKT, 256, 0, stream>>>(bcur, bpairs, offs, ends, pairs);

    // layer 0 (agg + transform + pre) -> G1,R1 (set A)
    k_l0pre<<<NN / 16, 256, 0, stream>>>(
        offs, ends, pairs, x, Wrel0, brel0, Wroot0,
        WgH, WgL, WrH, WrL, brel_mid, GbA, RbA);

    // mid layer 1: consume set A, produce set B (weights index 1)
    k_aggfused<false><<<NN / 16, 256, 0, stream>>>(
        offs, ends, pairs, GbA, RbA,
        WgH + 4096, WgL + 4096, WrH + 4096, WrL + 4096, brel_mid + HID,
        GbB, RbB, WrelL, WrootL, sarr, rarr);
    // mid layer 2: consume set B, produce set A (weights index 2)
    k_aggfused<false><<<NN / 16, 256, 0, stream>>>(
        offs, ends, pairs, GbB, RbB,
        WgH + 2 * 4096, WgL + 2 * 4096, WrH + 2 * 4096, WrL + 2 * 4096,
        brel_mid + 2 * HID, GbA, RbA, WrelL, WrootL, sarr, rarr);
    // mid layer 3 (LAST): consume set A, produce s/r scalars
    k_aggfused<true><<<NN / 16, 256, 0, stream>>>(
        offs, ends, pairs, GbA, RbA,
        WgH, WgL, WrH, WrL, brel_mid,
        GbB, RbB, WrelL, WrootL, sarr, rarr);

    // final edge pass on scalars
    k_last<<<(NN + 255) / 256, 256, 0, stream>>>(offs, ends, pairs, sarr, rarr, brelL, out);
}